// Round 17
// baseline (91.152 us; speedup 1.0000x reference)
//
#include <hip/hip_runtime.h>
#include <math.h>

#define NB    16
#define NP    4096
#define BXR   128            // x-rows per block (4 waves x 32)
#define NBLK  (NB * (NP / BXR) * 2)   // 1024 blocks

typedef _Float16 f16;
typedef _Float16 f16x4  __attribute__((ext_vector_type(4)));
typedef _Float16 f16x8  __attribute__((ext_vector_type(8)));
typedef float    f32x16 __attribute__((ext_vector_type(16)));

// R16 post-mortem: inferred kernel time (~27-31us) is 2.5x the per-pipe model
// (~10-13us) and has been insensitive to three structural rewrites. DIAGNOSTIC
// ROUND: identical kernel launched TWICE (idempotent part[] writes) -- the
// dur_us delta vs R16 directly measures the kernel's true cost, separating
// "kernel is slow" from "per-replay harness overhead floor".
// Kernel unchanged from R16: A = y (LDS), B = x (fixed) -> D col = lane's x
// [m74]; min-over-y is lane-local; one shfl_xor(32) merges half-waves. Bias
// rides k=3 (A.k3=-0.5||y||^2, B.k3=1); B's k>=4 zeros make A's high slots
// don't-care. Inner iter: 2 ds_read_b64 + 2 MFMA 32x32x16 + 16 v_max3.
__global__ __launch_bounds__(256, 4) void chamfer_mfma_kernel(
    const float* __restrict__ A1, const float* __restrict__ A2,
    float* __restrict__ part)
{
    __shared__ f16x4 sy[NP];     // 32 KB -> 4 blocks/CU
    __shared__ float sacc[4];
    const int b   = blockIdx.x;
    const int xc  = blockIdx.y;  // x-chunk (NP/BXR = 32)
    const int dir = blockIdx.z;
    const float* X = dir ? A2 : A1;
    const float* Y = dir ? A1 : A2;

    const int tid  = threadIdx.x;
    const int lane = tid & 63;
    const int w    = tid >> 6;   // 0..3
    const int col  = lane & 31;

    // Stage ALL 4096 y: f16 coords + f16 bias (from rounded coords) in elem 3.
    const float* Yb = Y + (size_t)b * NP * 3;
    for (int i = tid; i < NP; i += 256) {
        const float fx = Yb[3 * i], fy = Yb[3 * i + 1], fz = Yb[3 * i + 2];
        const f16 hx = (f16)fx, hy = (f16)fy, hz = (f16)fz;
        const float xx = (float)hx, yy = (float)hy, zz = (float)hz;
        sy[i] = (f16x4){hx, hy, hz, (f16)(-0.5f * (xx * xx + yy * yy + zz * zz))};
    }

    // B-frag: my x-point (col) in k=0..3 of lanes<32; everything else zero.
    const int xbase = xc * BXR + w * 32;
    const float* p = X + ((size_t)b * NP + xbase + col) * 3;
    const f16 ahx = (f16)p[0], ahy = (f16)p[1], ahz = (f16)p[2];
    const float axx = (float)ahx, ayy = (float)ahy, azz = (float)ahz;
    const float nax = -0.5f * (axx * axx + ayy * ayy + azz * azz);
    f16x8 bfr = (f16x8)(f16)0.f;
    if (lane < 32)
        bfr = (f16x8){ahx, ahy, ahz, (f16)1.0f,
                      (f16)0.f, (f16)0.f, (f16)0.f, (f16)0.f};
    __syncthreads();

    f32x16 mx;
    #pragma unroll
    for (int r = 0; r < 16; ++r) mx[r] = -3.3e38f;
    const f32x16 Z = {};

    // 64 iters x 2 y-tiles; 1-ahead ds prefetch. Lanes 32-63 dup-read (ok).
    f16x4 q0 = sy[col];
    f16x4 q1 = sy[32 + col];
    #pragma unroll 2
    for (int j = 0; j < NP / 64; ++j) {
        const int jn = (j + 1) & (NP / 64 - 1);
        const f16x4 p0 = sy[jn * 64 + col];
        const f16x4 p1 = sy[jn * 64 + 32 + col];
        const f16x8 a0 = __builtin_shufflevector(q0, q0, 0, 1, 2, 3, -1, -1, -1, -1);
        const f16x8 a1 = __builtin_shufflevector(q1, q1, 0, 1, 2, 3, -1, -1, -1, -1);
        const f32x16 d0 =
            __builtin_amdgcn_mfma_f32_32x32x16_f16(a0, bfr, Z, 0, 0, 0);
        const f32x16 d1 =
            __builtin_amdgcn_mfma_f32_32x32x16_f16(a1, bfr, Z, 0, 0, 0);
        #pragma unroll
        for (int r = 0; r < 16; ++r)
            mx[r] = fmaxf(fmaxf(mx[r], d0[r]), d1[r]);   // v_max3_f32
        q0 = p0; q1 = p1;
    }

    // Lane-local tree (8 ops) + half-wave merge (1 shfl) + e/sqrt/sum.
    #define F3(a, bb, c) fmaxf(fmaxf((a), (bb)), (c))
    const float t0 = F3(mx[0],  mx[1],  mx[2]);
    const float t1 = F3(mx[3],  mx[4],  mx[5]);
    const float t2 = F3(mx[6],  mx[7],  mx[8]);
    const float t3 = F3(mx[9],  mx[10], mx[11]);
    const float t4 = F3(mx[12], mx[13], mx[14]);
    float v = fmaxf(F3(t0, t1, t2), F3(t3, t4, mx[15]));
    #undef F3
    v = fmaxf(v, __shfl_xor(v, 32, 64));     // rows split across half-waves

    const float e = fmaxf(-(nax + v), 0.0f); // = d_min/2, exact >= 0
    float s = (lane < 32) ? sqrtf(2.0f * e) : 0.0f;   // count each x once
    #pragma unroll
    for (int off = 32; off > 0; off >>= 1)
        s += __shfl_down(s, off, 64);

    if (lane == 0) sacc[w] = s;
    __syncthreads();
    if (tid == 0) {
        const int bid = blockIdx.x + NB * (blockIdx.y + (NP / BXR) * blockIdx.z);
        part[bid] = (sacc[0] + sacc[1]) + (sacc[2] + sacc[3]);
    }
}

// One block: sum the 1024 per-block partials, write out[0] directly.
__global__ __launch_bounds__(1024) void final_reduce_kernel(
    const float* __restrict__ part, float* __restrict__ out)
{
    float s = part[threadIdx.x];   // NBLK == 1024
    #pragma unroll
    for (int off = 32; off > 0; off >>= 1)
        s += __shfl_down(s, off, 64);

    __shared__ float ws[16];
    const int lane = threadIdx.x & 63;
    const int wid  = threadIdx.x >> 6;
    if (lane == 0) ws[wid] = s;
    __syncthreads();
    if (threadIdx.x == 0) {
        float t = 0.0f;
        #pragma unroll
        for (int v = 0; v < 16; ++v) t += ws[v];
        // out = (sum1+sum2) * 1000 / (2 * NB * NP); 1000/131072 exact in fp32.
        out[0] = t * 0.00762939453125f;
    }
}

extern "C" void kernel_launch(void* const* d_in, const int* in_sizes, int n_in,
                              void* d_out, int out_size, void* d_ws, size_t ws_size,
                              hipStream_t stream)
{
    const float* a1 = (const float*)d_in[0];  // [NB, NP, 3] fp32
    const float* a2 = (const float*)d_in[1];  // [NB, NP, 3] fp32
    float* out = (float*)d_out;
    float* part = (float*)d_ws;               // [NBLK] floats (4 KB)

    dim3 grid(NB, NP / BXR, 2);   // 16 x 32 x 2 = 1024 blocks, 4/CU
    // DIAGNOSTIC: two identical launches (idempotent). dur_us delta vs R16
    // (74.3us) == true kernel cost, independent of the 40us fill dispatches.
    chamfer_mfma_kernel<<<grid, 256, 0, stream>>>(a1, a2, part);
    chamfer_mfma_kernel<<<grid, 256, 0, stream>>>(a1, a2, part);

    final_reduce_kernel<<<1, 1024, 0, stream>>>(part, out);
}

// Round 18
// 74.926 us; speedup vs baseline: 1.2166x; 1.2166x over previous
//
#include <hip/hip_runtime.h>
#include <math.h>

#define NB    16
#define NP    4096
#define BXR   256            // x-rows per block: 4 waves x 64 (2 tiles of 32)
#define NBLK  (NB * (NP / BXR) * 2)   // 512 blocks

typedef _Float16 f16;
typedef _Float16 f16x4  __attribute__((ext_vector_type(4)));
typedef _Float16 f16x8  __attribute__((ext_vector_type(8)));
typedef float    f32x16 __attribute__((ext_vector_type(16)));

// R17 diagnostic: true kernel cost 16.9us (74.3 total = 40 fill + ~15 replay
// overhead + 17 kernel + 2 reduce). This round: TWO B-frags (x-tiles) per
// wave -> each A-frag (y) feeds 2 MFMAs; per-pair LDS reads halve, staging
// halves (512 blocks). A-frag high-k = the OTHER quad (finite, killed by B's
// k4..7 zeros -- no undef). Per iter: 2 ds_read_b64 + 4 MFMA + 32 v_max3
// covering 64y x 64x. 2 blocks/CU (LDS 32KB), launch_bounds(256,2) = no
// spill risk. Bias rides k=3 (A.k3=-0.5||y||^2, B.k3=1); min-over-y is
// lane-local [m74: D col = lane&31]; one shfl_xor(32) merges half-waves.
__global__ __launch_bounds__(256, 2) void chamfer_mfma_kernel(
    const float* __restrict__ A1, const float* __restrict__ A2,
    float* __restrict__ part)
{
    __shared__ f16x4 sy[NP];     // 32 KB -> 2 blocks/CU
    __shared__ float sacc[4];
    const int b   = blockIdx.x;
    const int xc  = blockIdx.y;  // x-chunk (NP/BXR = 16)
    const int dir = blockIdx.z;
    const float* X = dir ? A2 : A1;
    const float* Y = dir ? A1 : A2;

    const int tid  = threadIdx.x;
    const int lane = tid & 63;
    const int w    = tid >> 6;   // 0..3
    const int col  = lane & 31;

    // Stage ALL 4096 y: f16 coords + f16 bias (from rounded coords) in elem 3.
    const float* Yb = Y + (size_t)b * NP * 3;
    for (int i = tid; i < NP; i += 256) {
        const float fx = Yb[3 * i], fy = Yb[3 * i + 1], fz = Yb[3 * i + 2];
        const f16 hx = (f16)fx, hy = (f16)fy, hz = (f16)fz;
        const float xx = (float)hx, yy = (float)hy, zz = (float)hz;
        sy[i] = (f16x4){hx, hy, hz, (f16)(-0.5f * (xx * xx + yy * yy + zz * zz))};
    }

    // Two B-frags: x-points (xbase+col) and (xbase+32+col), k=0..3 of lanes<32.
    const int xbase = xc * BXR + w * 64;
    const float* p0 = X + ((size_t)b * NP + xbase + col) * 3;
    const float* p1 = X + ((size_t)b * NP + xbase + 32 + col) * 3;
    const f16 h0x = (f16)p0[0], h0y = (f16)p0[1], h0z = (f16)p0[2];
    const f16 h1x = (f16)p1[0], h1y = (f16)p1[1], h1z = (f16)p1[2];
    const float a0x = (float)h0x, a0y = (float)h0y, a0z = (float)h0z;
    const float a1x = (float)h1x, a1y = (float)h1y, a1z = (float)h1z;
    const float nax0 = -0.5f * (a0x * a0x + a0y * a0y + a0z * a0z);
    const float nax1 = -0.5f * (a1x * a1x + a1y * a1y + a1z * a1z);
    f16x8 bfr0 = (f16x8)(f16)0.f, bfr1 = (f16x8)(f16)0.f;
    if (lane < 32) {
        bfr0 = (f16x8){h0x, h0y, h0z, (f16)1.0f,
                       (f16)0.f, (f16)0.f, (f16)0.f, (f16)0.f};
        bfr1 = (f16x8){h1x, h1y, h1z, (f16)1.0f,
                       (f16)0.f, (f16)0.f, (f16)0.f, (f16)0.f};
    }
    __syncthreads();

    f32x16 mx0, mx1;
    #pragma unroll
    for (int r = 0; r < 16; ++r) { mx0[r] = -3.3e38f; mx1[r] = -3.3e38f; }
    const f32x16 Z = {};

    // 64 iters x 64 y; 1-ahead ds prefetch. Lanes 32-63 dup-read (broadcast).
    f16x4 q0 = sy[col];
    f16x4 q1 = sy[32 + col];
    #pragma unroll 2
    for (int j = 0; j < NP / 64; ++j) {
        const int jn = (j + 1) & (NP / 64 - 1);
        const f16x4 n0 = sy[jn * 64 + col];
        const f16x4 n1 = sy[jn * 64 + 32 + col];
        // a0: y-tile 2j in k0..3 (high k = other quad, finite, B-zero-killed)
        const f16x8 a0 = __builtin_shufflevector(q0, q1, 0, 1, 2, 3, 4, 5, 6, 7);
        const f16x8 a1 = __builtin_shufflevector(q1, q0, 0, 1, 2, 3, 4, 5, 6, 7);
        const f32x16 d00 =
            __builtin_amdgcn_mfma_f32_32x32x16_f16(a0, bfr0, Z, 0, 0, 0);
        const f32x16 d10 =
            __builtin_amdgcn_mfma_f32_32x32x16_f16(a1, bfr0, Z, 0, 0, 0);
        const f32x16 d01 =
            __builtin_amdgcn_mfma_f32_32x32x16_f16(a0, bfr1, Z, 0, 0, 0);
        const f32x16 d11 =
            __builtin_amdgcn_mfma_f32_32x32x16_f16(a1, bfr1, Z, 0, 0, 0);
        #pragma unroll
        for (int r = 0; r < 16; ++r) {
            mx0[r] = fmaxf(fmaxf(mx0[r], d00[r]), d10[r]);   // v_max3_f32
            mx1[r] = fmaxf(fmaxf(mx1[r], d01[r]), d11[r]);
        }
        q0 = n0; q1 = n1;
    }

    // Lane-local trees + half-wave merges + e/sqrt/sum (2 x-points per lane).
    #define F3(a, bb, c) fmaxf(fmaxf((a), (bb)), (c))
    float v0, v1;
    {
        const float t0 = F3(mx0[0],  mx0[1],  mx0[2]);
        const float t1 = F3(mx0[3],  mx0[4],  mx0[5]);
        const float t2 = F3(mx0[6],  mx0[7],  mx0[8]);
        const float t3 = F3(mx0[9],  mx0[10], mx0[11]);
        const float t4 = F3(mx0[12], mx0[13], mx0[14]);
        v0 = fmaxf(F3(t0, t1, t2), F3(t3, t4, mx0[15]));
        const float u0 = F3(mx1[0],  mx1[1],  mx1[2]);
        const float u1 = F3(mx1[3],  mx1[4],  mx1[5]);
        const float u2 = F3(mx1[6],  mx1[7],  mx1[8]);
        const float u3 = F3(mx1[9],  mx1[10], mx1[11]);
        const float u4 = F3(mx1[12], mx1[13], mx1[14]);
        v1 = fmaxf(F3(u0, u1, u2), F3(u3, u4, mx1[15]));
    }
    #undef F3
    v0 = fmaxf(v0, __shfl_xor(v0, 32, 64));   // rows split across half-waves
    v1 = fmaxf(v1, __shfl_xor(v1, 32, 64));

    const float e0 = fmaxf(-(nax0 + v0), 0.0f);   // = d_min/2, exact >= 0
    const float e1 = fmaxf(-(nax1 + v1), 0.0f);
    float s = (lane < 32) ? (sqrtf(2.0f * e0) + sqrtf(2.0f * e1)) : 0.0f;
    #pragma unroll
    for (int off = 32; off > 0; off >>= 1)
        s += __shfl_down(s, off, 64);

    if (lane == 0) sacc[w] = s;
    __syncthreads();
    if (tid == 0) {
        const int bid = blockIdx.x + NB * (blockIdx.y + (NP / BXR) * blockIdx.z);
        part[bid] = (sacc[0] + sacc[1]) + (sacc[2] + sacc[3]);
    }
}

// One block: sum the 512 per-block partials, write out[0] directly.
__global__ __launch_bounds__(512) void final_reduce_kernel(
    const float* __restrict__ part, float* __restrict__ out)
{
    float s = part[threadIdx.x];   // NBLK == 512
    #pragma unroll
    for (int off = 32; off > 0; off >>= 1)
        s += __shfl_down(s, off, 64);

    __shared__ float ws[8];
    const int lane = threadIdx.x & 63;
    const int wid  = threadIdx.x >> 6;
    if (lane == 0) ws[wid] = s;
    __syncthreads();
    if (threadIdx.x == 0) {
        float t = 0.0f;
        #pragma unroll
        for (int v = 0; v < 8; ++v) t += ws[v];
        // out = (sum1+sum2) * 1000 / (2 * NB * NP); 1000/131072 exact in fp32.
        out[0] = t * 0.00762939453125f;
    }
}

extern "C" void kernel_launch(void* const* d_in, const int* in_sizes, int n_in,
                              void* d_out, int out_size, void* d_ws, size_t ws_size,
                              hipStream_t stream)
{
    const float* a1 = (const float*)d_in[0];  // [NB, NP, 3] fp32
    const float* a2 = (const float*)d_in[1];  // [NB, NP, 3] fp32
    float* out = (float*)d_out;
    float* part = (float*)d_ws;               // [NBLK] floats (2 KB)

    dim3 grid(NB, NP / BXR, 2);   // 16 x 16 x 2 = 512 blocks, 2/CU
    chamfer_mfma_kernel<<<grid, 256, 0, stream>>>(a1, a2, part);

    final_reduce_kernel<<<1, 512, 0, stream>>>(part, out);
}